// Round 1
// baseline (174.778 us; speedup 1.0000x reference)
//
#include <hip/hip_runtime.h>
#include <hip/hip_bf16.h>

// Problem constants (match reference)
#define NB    2048    // graphs
#define NUMK  128     // nodes per graph
#define NE    1024    // edges per graph template
#define HID   32      // hidden width
#define ROWLEN (NUMK + NE + 2)   // 1154 floats per Hx row

// ---------------------------------------------------------------------------
// Setup kernel: build CSR-by-dst of the shared edge template into workspace.
// packed[slot] = src | (edge_id << 7); row_off[129] gives per-dst slot ranges.
// Runs once per launch (1 block, 1024 threads, one edge per thread).
// ---------------------------------------------------------------------------
__global__ __launch_bounds__(1024) void build_csr_kernel(
    const int* __restrict__ ei,        // edge_index [2, NE] as int32
    unsigned* __restrict__ row_off,    // [NUMK+1]
    unsigned* __restrict__ packed)     // [NE]
{
    __shared__ unsigned cnt[NUMK];
    __shared__ unsigned incl[NUMK];
    __shared__ unsigned cur[NUMK];
    const int t = threadIdx.x;

    if (t < NUMK) cnt[t] = 0u;
    __syncthreads();

    const int dst = ei[NE + t] & (NUMK - 1);
    atomicAdd(&cnt[dst], 1u);
    __syncthreads();

    // exclusive prefix sum over 128 counts: per-wave shfl scan (2 waves)
    if (t < NUMK) {
        unsigned v = cnt[t];
        #pragma unroll
        for (int d = 1; d < 64; d <<= 1) {
            unsigned u = __shfl_up(v, d, 64);
            if ((t & 63) >= d) v += u;
        }
        incl[t] = v;   // inclusive scan within wave
    }
    __syncthreads();
    if (t < NUMK) {
        unsigned base = (t >= 64) ? incl[63] : 0u;
        unsigned offv = base + incl[t] - cnt[t];   // exclusive
        row_off[t] = offv;
        cur[t]     = offv;
    }
    if (t == 0) row_off[NUMK] = (unsigned)NE;      // total is always NE
    __syncthreads();

    const int src = ei[t] & (NUMK - 1);
    const unsigned pos = atomicAdd(&cur[dst], 1u);
    packed[pos] = (unsigned)src | ((unsigned)t << 7);
}

// ---------------------------------------------------------------------------
// Main kernel: one block per graph. Entire graph state lives in LDS.
//   L1: a0 = Agg(p)          (scalar aggregation; W1 is [1,32] so Agg commutes)
//   x1 = relu(a0 ⊗ W1 + b1)  [128][32]
//   a1 = Agg(x1)             (32-wide aggregation, conflict-free via stride 33)
//   x2 = relu(a1 @ W2 + b2)
//   s  = x2 @ W3             (per-node dot; W3 is [32,1])
//   out = Agg(s) + b3
// ---------------------------------------------------------------------------
__global__ __launch_bounds__(256) void gcn_main_kernel(
    const float* __restrict__ Hx,
    const float* __restrict__ W1, const float* __restrict__ b1,
    const float* __restrict__ W2, const float* __restrict__ b2,
    const float* __restrict__ W3, const float* __restrict__ b3,
    const unsigned* __restrict__ row_off_g,
    const unsigned* __restrict__ packed_g,
    float* __restrict__ out)
{
    __shared__ float    wsh[NE];            // per-graph edge weights
    __shared__ unsigned pk[NE];             // CSR slots: src | (eid<<7)
    __shared__ float    normv[NE];          // per-slot norm coefficient
    __shared__ float    w2s[HID * HID];     // W2, row-major [k][j]
    __shared__ float    x1b[NUMK * 33];     // x1 then x2 (stride 33: bank-safe)
    __shared__ float    a1b[NUMK * 33];     // Agg(x1)
    __shared__ float    pbuf[NUMK], dinv[NUMK], selfn[NUMK], a0[NUMK], sbuf[NUMK];
    __shared__ float    w1s[HID], b1s[HID], b2s[HID], w3s[HID];
    __shared__ unsigned roff[NUMK + 1];

    const int tid = threadIdx.x;
    const int g   = blockIdx.x;
    const float* rowp = Hx + (size_t)g * ROWLEN;

    // ---- stage: global -> LDS (coalesced) ----
    if (tid < NUMK) pbuf[tid] = rowp[tid];
    for (int t = tid; t < NE; t += 256) {
        wsh[t] = rowp[NUMK + t];
        pk[t]  = packed_g[t];
        w2s[t] = W2[t];
    }
    if (tid <= NUMK) roff[tid] = row_off_g[tid];
    if (tid >= 128 && tid < 160) {
        int j = tid - 128;
        w1s[j] = W1[j]; b1s[j] = b1[j]; b2s[j] = b2[j]; w3s[j] = W3[j];
    }
    __syncthreads();

    // ---- deg / dinv (thread per node) ----
    if (tid < NUMK) {
        float d = 1.0f;                          // self-loop weight
        const unsigned k0 = roff[tid], k1 = roff[tid + 1];
        for (unsigned k = k0; k < k1; ++k) d += wsh[pk[k] >> 7];
        const float di = rsqrtf(d);              // deg >= 1 always
        dinv[tid]  = di;
        selfn[tid] = di * di;
    }
    __syncthreads();

    // ---- norm coefficients + scalar aggregation of p (layer-1 propagate) ----
    if (tid < NUMK) {
        const float di = dinv[tid];
        float acc = selfn[tid] * pbuf[tid];
        const unsigned k0 = roff[tid], k1 = roff[tid + 1];
        for (unsigned k = k0; k < k1; ++k) {
            const unsigned u = pk[k];
            const int src = (int)(u & (NUMK - 1));
            const float nv = di * dinv[src] * wsh[u >> 7];
            normv[k] = nv;
            acc = fmaf(nv, pbuf[src], acc);
        }
        a0[tid] = acc;
    }
    __syncthreads();

    // ---- x1 = relu(a0 * W1 + b1) ----
    for (int t = tid; t < NUMK * HID; t += 256) {
        const int i = t >> 5, j = t & 31;
        const float v = fmaf(a0[i], w1s[j], b1s[j]);
        x1b[i * 33 + j] = v > 0.f ? v : 0.f;
    }
    __syncthreads();

    // ---- a1 = Agg(x1): group of 32 lanes per node, lane = hidden dim ----
    {
        const int lane = tid & 31, grp = tid >> 5;   // 8 groups
        for (int i = grp; i < NUMK; i += 8) {
            float acc = selfn[i] * x1b[i * 33 + lane];
            const unsigned k0 = roff[i], k1 = roff[i + 1];
            for (unsigned k = k0; k < k1; ++k) {
                const unsigned u = pk[k];
                acc = fmaf(normv[k], x1b[(int)(u & (NUMK - 1)) * 33 + lane], acc);
            }
            a1b[i * 33 + lane] = acc;
        }
    }
    __syncthreads();

    // ---- x2 = relu(a1 @ W2 + b2), written over x1b ----
    {
        const int j = tid & 31, i0 = tid >> 5;
        float wcol[HID];                 // j is thread-invariant: hoist W2 column
        #pragma unroll
        for (int k = 0; k < HID; ++k) wcol[k] = w2s[k * HID + j];
        for (int i = i0; i < NUMK; i += 8) {
            float acc = b2s[j];
            #pragma unroll
            for (int k = 0; k < HID; ++k) acc = fmaf(a1b[i * 33 + k], wcol[k], acc);
            x1b[i * 33 + j] = acc > 0.f ? acc : 0.f;
        }
    }
    __syncthreads();

    // ---- s = x2 @ W3 (per-node dot; stride 33 keeps banks distinct) ----
    if (tid < NUMK) {
        float acc = 0.f;
        #pragma unroll
        for (int j = 0; j < HID; ++j) acc = fmaf(x1b[tid * 33 + j], w3s[j], acc);
        sbuf[tid] = acc;
    }
    __syncthreads();

    // ---- out = Agg(s) + b3 ----
    if (tid < NUMK) {
        float acc = selfn[tid] * sbuf[tid];
        const unsigned k0 = roff[tid], k1 = roff[tid + 1];
        for (unsigned k = k0; k < k1; ++k)
            acc = fmaf(normv[k], sbuf[pk[k] & (NUMK - 1)], acc);
        out[(size_t)g * NUMK + tid] = acc + b3[0];
    }
}

extern "C" void kernel_launch(void* const* d_in, const int* in_sizes, int n_in,
                              void* d_out, int out_size, void* d_ws, size_t ws_size,
                              hipStream_t stream) {
    const float* Hx = (const float*)d_in[0];
    const int*   ei = (const int*)d_in[1];     // harness delivers integers as int32
    const float* W1 = (const float*)d_in[2];
    const float* b1 = (const float*)d_in[3];
    const float* W2 = (const float*)d_in[4];
    const float* b2 = (const float*)d_in[5];
    const float* W3 = (const float*)d_in[6];
    const float* b3 = (const float*)d_in[7];
    float* out = (float*)d_out;

    unsigned* packed  = (unsigned*)d_ws;           // [NE]
    unsigned* row_off = packed + NE;               // [NUMK+1]

    build_csr_kernel<<<1, 1024, 0, stream>>>(ei, row_off, packed);
    gcn_main_kernel<<<NB, 256, 0, stream>>>(Hx, W1, b1, W2, b2, W3, b3,
                                            row_off, packed, out);
}

// Round 2
// 117.490 us; speedup vs baseline: 1.4876x; 1.4876x over previous
//
#include <hip/hip_runtime.h>
#include <hip/hip_bf16.h>

// Problem constants (match reference)
#define NB    2048
#define NUMK  128
#define NE    1024
#define HID   32
#define ROWLEN (NUMK + NE + 2)
#define NSLOT (NE + NUMK)        // edges + self-loops = 1152

// ---------------------------------------------------------------------------
// Setup kernel: degree-sorted CSR (by dst) of the shared template, with
// self-loops folded in as regular slots (eid = NE, weight 1).
//   packed[slot] = src | (eid << 7)
//   row_off[r]   = slot range of the node with degree-rank r
//   nor[r]       = node id of rank r
// Degree-ranking makes slot-loop trip counts uniform within a wave.
// ---------------------------------------------------------------------------
__global__ __launch_bounds__(1024) void build_csr_kernel(
    const int* __restrict__ ei,
    unsigned* __restrict__ row_off,    // [NUMK+1]
    unsigned* __restrict__ packed,     // [NSLOT]
    unsigned* __restrict__ nor_g)      // [NUMK]
{
    __shared__ unsigned cnt[NUMK], rk[NUMK], nor[NUMK];
    __shared__ unsigned cntr[NUMK], incl[NUMK], cur[NUMK];
    const int t = threadIdx.x;

    if (t < NUMK) cnt[t] = 1u;                 // self slot
    __syncthreads();
    const int dst = ei[NE + t] & (NUMK - 1);
    atomicAdd(&cnt[dst], 1u);
    __syncthreads();

    // rank nodes by slot count, descending (stable)
    if (t < NUMK) {
        const unsigned c = cnt[t];
        unsigned r = 0;
        for (int j = 0; j < NUMK; ++j) {
            const unsigned cj = cnt[j];
            r += (cj > c) || (cj == c && j < t);
        }
        rk[t] = r; nor[r] = t;
    }
    __syncthreads();
    if (t < NUMK) cntr[t] = cnt[nor[t]];
    __syncthreads();

    // exclusive scan over rank-ordered counts (two 64-lane wave scans)
    if (t < NUMK) {
        unsigned v = cntr[t];
        #pragma unroll
        for (int d = 1; d < 64; d <<= 1) {
            unsigned u = __shfl_up(v, d, 64);
            if ((t & 63) >= d) v += u;
        }
        incl[t] = v;
    }
    __syncthreads();
    if (t < NUMK) {
        const unsigned base = (t >= 64) ? incl[63] : 0u;
        const unsigned off  = base + incl[t] - cntr[t];
        row_off[t] = off; cur[t] = off;
        nor_g[t]   = nor[t];
    }
    if (t == 0) row_off[NUMK] = (unsigned)NSLOT;
    __syncthreads();

    // scatter edges, then self slots
    {
        const int src = ei[t] & (NUMK - 1);
        const unsigned pos = atomicAdd(&cur[rk[dst]], 1u);
        packed[pos] = (unsigned)src | ((unsigned)t << 7);
    }
    if (t < NUMK) {
        const unsigned pos = atomicAdd(&cur[rk[t]], 1u);
        packed[pos] = (unsigned)t | ((unsigned)NE << 7);
    }
}

// ---------------------------------------------------------------------------
// Main kernel: one block (256 thr) per graph.
//   P1  deg -> dinv (per rank)
//   P2  norm coefficients + scalar p-aggregation (a0)      [x1 is rank-1!]
//   P3  pack (norm, a0[src]) per slot as float2
//   P4  fused: a1 = Agg(relu(a0 w1 + b1)) -> x2 = relu(a1@W2+b2) -> s = x2@W3
//       16-lane groups, 2 hidden dims per lane, slot loop = 1 bcast b64 + 4 fma
//   P5  out = Agg(s) + b3
// ---------------------------------------------------------------------------
__global__ __launch_bounds__(256) void gcn_main_kernel(
    const float* __restrict__ Hx,
    const float* __restrict__ W1, const float* __restrict__ b1,
    const float* __restrict__ W2, const float* __restrict__ b2,
    const float* __restrict__ W3, const float* __restrict__ b3,
    const unsigned* __restrict__ row_off_g,
    const unsigned* __restrict__ packed_g,
    const unsigned* __restrict__ nor_g,
    float* __restrict__ out)
{
    __shared__ unsigned pk[NSLOT];          // src | (eid<<7); eid==NE -> self
    __shared__ float    wsh[NE + 2];        // edge weights; wsh[NE] = 1
    __shared__ float2   ns[NSLOT];          // (norm, a0[src]) per slot
    __shared__ float    w2s[HID * HID];     // W2 row-major [k][j]
    __shared__ float    pbuf[NUMK], dinvb[NUMK], a0b[NUMK], sbuf[NUMK];
    __shared__ float    a1buf[16][HID];     // per-group a1 row scratch
    __shared__ unsigned roff[NUMK + 1], norb[NUMK];
    __shared__ float    w1s[HID], b1s[HID], b2s[HID], w3s[HID];

    const int tid = threadIdx.x;
    const float* rowp = Hx + (size_t)blockIdx.x * ROWLEN;

    // ---- stage ----
    if (tid < NUMK) pbuf[tid] = rowp[tid];
    for (int t = tid; t < NE; t += 256) {
        wsh[t] = rowp[NUMK + t];
        w2s[t] = W2[t];
    }
    for (int t = tid; t < NSLOT; t += 256) pk[t] = packed_g[t];
    if (tid == 0) wsh[NE] = 1.0f;
    if (tid < NUMK + 1) roff[tid] = row_off_g[tid];
    if (tid >= 128 && tid < 256) norb[tid - 128] = nor_g[tid - 128];
    if (tid >= 160 && tid < 192) {
        const int j = tid - 160;
        w1s[j] = W1[j]; b1s[j] = b1[j]; b2s[j] = b2[j]; w3s[j] = W3[j];
    }
    __syncthreads();

    // ---- P1: degree (sum of slot weights; self contributes 1) ----
    if (tid < NUMK) {
        const unsigned k0 = roff[tid], k1 = roff[tid + 1];
        float d = 0.f;
        for (unsigned k = k0; k < k1; ++k) d += wsh[pk[k] >> 7];
        dinvb[norb[tid]] = rsqrtf(d);        // deg >= 1 always
    }
    __syncthreads();

    // ---- P2: norm per slot + scalar p-aggregation ----
    if (tid < NUMK) {
        const int node = norb[tid];
        const float di = dinvb[node];
        const unsigned k0 = roff[tid], k1 = roff[tid + 1];
        float acc = 0.f;
        for (unsigned k = k0; k < k1; ++k) {
            const unsigned u = pk[k];
            const int src = (int)(u & (NUMK - 1));
            const float nv = di * dinvb[src] * wsh[u >> 7];
            ns[k].x = nv;
            acc = fmaf(nv, pbuf[src], acc);
        }
        a0b[node] = acc;
    }
    __syncthreads();

    // ---- P3: pack a0[src] next to norm ----
    for (int k = tid; k < NSLOT; k += 256) ns[k].y = a0b[pk[k] & (NUMK - 1)];
    __syncthreads();

    // ---- P4: fused agg + matmul + s-dot ----
    {
        const int grp = tid >> 4, l = tid & 15;
        const int j0 = 2 * l, j1 = j0 + 1;
        const float w1a = w1s[j0], w1b = w1s[j1];
        const float b1a = b1s[j0], b1b = b1s[j1];
        const float b2a = b2s[j0], b2b = b2s[j1];
        const float w3a = w3s[j0], w3b = w3s[j1];

        for (int m = 0; m < 8; ++m) {
            const int r = grp + (m << 4);            // rank
            const unsigned k0 = roff[r], k1 = roff[r + 1];
            float aa = 0.f, ab = 0.f;
            for (unsigned k = k0; k < k1; ++k) {
                const float2 nq = ns[k];             // broadcast b64
                float xa = fmaf(nq.y, w1a, b1a); xa = xa > 0.f ? xa : 0.f;
                float xb = fmaf(nq.y, w1b, b1b); xb = xb > 0.f ? xb : 0.f;
                aa = fmaf(nq.x, xa, aa);
                ab = fmaf(nq.x, xb, ab);
            }
            a1buf[grp][j0] = aa;
            a1buf[grp][j1] = ab;
            __threadfence_block();                   // LDS write->read order (same wave)
            float xa = b2a, xb = b2b;
            #pragma unroll
            for (int k = 0; k < HID; ++k) {
                const float av = a1buf[grp][k];      // broadcast, imm offset
                const float2 wv = *(const float2*)&w2s[k * HID + j0];
                xa = fmaf(av, wv.x, xa);
                xb = fmaf(av, wv.y, xb);
            }
            xa = xa > 0.f ? xa : 0.f; xb = xb > 0.f ? xb : 0.f;
            float sv = xa * w3a + xb * w3b;
            #pragma unroll
            for (int d2 = 8; d2 >= 1; d2 >>= 1) sv += __shfl_xor(sv, d2, 16);
            if (l == 0) sbuf[norb[r]] = sv;
        }
    }
    __syncthreads();

    // ---- P5: out = Agg(s) + b3 ----
    if (tid < NUMK) {
        const unsigned k0 = roff[tid], k1 = roff[tid + 1];
        float acc = 0.f;
        for (unsigned k = k0; k < k1; ++k)
            acc = fmaf(ns[k].x, sbuf[pk[k] & (NUMK - 1)], acc);
        out[(size_t)blockIdx.x * NUMK + norb[tid]] = acc + b3[0];
    }
}

extern "C" void kernel_launch(void* const* d_in, const int* in_sizes, int n_in,
                              void* d_out, int out_size, void* d_ws, size_t ws_size,
                              hipStream_t stream) {
    const float* Hx = (const float*)d_in[0];
    const int*   ei = (const int*)d_in[1];
    const float* W1 = (const float*)d_in[2];
    const float* b1 = (const float*)d_in[3];
    const float* W2 = (const float*)d_in[4];
    const float* b2 = (const float*)d_in[5];
    const float* W3 = (const float*)d_in[6];
    const float* b3 = (const float*)d_in[7];
    float* out = (float*)d_out;

    unsigned* packed  = (unsigned*)d_ws;           // [NSLOT]
    unsigned* row_off = packed + NSLOT;            // [NUMK+1]
    unsigned* nor     = row_off + (NUMK + 1);      // [NUMK]

    build_csr_kernel<<<1, 1024, 0, stream>>>(ei, row_off, packed, nor);
    gcn_main_kernel<<<NB, 256, 0, stream>>>(Hx, W1, b1, W2, b2, W3, b3,
                                            row_off, packed, nor, out);
}

// Round 3
// 108.267 us; speedup vs baseline: 1.6143x; 1.0852x over previous
//
#include <hip/hip_runtime.h>
#include <hip/hip_bf16.h>

#define NB    2048
#define NUMK  128
#define NE    1024
#define HID   32
#define ROWLEN (NUMK + NE + 2)
#define NSLOT (NE + NUMK)        // edges + self-loops = 1152
#define ASTRIDE 136              // bf16 elems per Â row (128 + 8 pad)
#define A1STRIDE 40              // bf16 elems per a1/W2T row (32 + 8 pad)

using s8  = __attribute__((ext_vector_type(8))) short;   // 8 bf16 (A/B frag)
using f4  = __attribute__((ext_vector_type(4))) float;   // C/D frag
using fl4 = __attribute__((ext_vector_type(4))) float;

static __device__ __forceinline__ unsigned short f2bf(float f) {
    unsigned u = __float_as_uint(f);
    unsigned r = (u + 0x7fffu + ((u >> 16) & 1u)) >> 16;   // RNE
    return (unsigned short)r;
}
static __device__ __forceinline__ float bf2f(unsigned short h) {
    return __uint_as_float(((unsigned)h) << 16);
}

// ---------------------------------------------------------------------------
// Setup: degree-ranked CSR (by dst) of the shared template, self-loops folded
// in (eid = NE). packed[slot] = src_RANK | (eid << 7). Rank space everywhere;
// nor[r] = node id of rank r (for I/O gather/scatter).
// ---------------------------------------------------------------------------
__global__ __launch_bounds__(1024) void build_csr_kernel(
    const int* __restrict__ ei,
    unsigned* __restrict__ row_off,    // [NUMK+1]
    unsigned* __restrict__ packed,     // [NSLOT]
    unsigned* __restrict__ nor_g)      // [NUMK]
{
    __shared__ unsigned cnt[NUMK], rk[NUMK], nor[NUMK];
    __shared__ unsigned cntr[NUMK], incl[NUMK], cur[NUMK];
    const int t = threadIdx.x;

    if (t < NUMK) cnt[t] = 1u;                 // self slot
    __syncthreads();
    const int dst = ei[NE + t] & (NUMK - 1);
    atomicAdd(&cnt[dst], 1u);
    __syncthreads();

    if (t < NUMK) {
        const unsigned c = cnt[t];
        unsigned r = 0;
        for (int j = 0; j < NUMK; ++j) {
            const unsigned cj = cnt[j];
            r += (cj > c) || (cj == c && j < t);
        }
        rk[t] = r; nor[r] = t;
    }
    __syncthreads();
    if (t < NUMK) cntr[t] = cnt[nor[t]];
    __syncthreads();

    if (t < NUMK) {
        unsigned v = cntr[t];
        #pragma unroll
        for (int d = 1; d < 64; d <<= 1) {
            unsigned u = __shfl_up(v, d, 64);
            if ((t & 63) >= d) v += u;
        }
        incl[t] = v;
    }
    __syncthreads();
    if (t < NUMK) {
        const unsigned base = (t >= 64) ? incl[63] : 0u;
        const unsigned off  = base + incl[t] - cntr[t];
        row_off[t] = off; cur[t] = off;
        nor_g[t]   = nor[t];
    }
    if (t == 0) row_off[NUMK] = (unsigned)NSLOT;
    __syncthreads();

    {
        const int src = ei[t] & (NUMK - 1);
        const unsigned pos = atomicAdd(&cur[rk[dst]], 1u);
        packed[pos] = rk[src] | ((unsigned)t << 7);
    }
    if (t < NUMK) {
        const unsigned pos = atomicAdd(&cur[rk[t]], 1u);
        packed[pos] = rk[t] | ((unsigned)NE << 7);
    }
}

// ---------------------------------------------------------------------------
// Main: one block (256 thr = 4 waves) per graph. Rank space throughout.
//  P1 stage (+ zero Â)          P2 deg->dinv        P3 norms + a0 + Â scatter
//  P4 a1 = Â @ x1 (MFMA, x1 on the fly)   P5 a1 -> LDS bf16 (reuse Â region)
//  P6 x2 = relu(a1@W2+b2) (MFMA) + s = x2@W3 (shfl)  P7 out = Agg(s)+b3
// ---------------------------------------------------------------------------
__global__ __launch_bounds__(256) void gcn_main_kernel(
    const float* __restrict__ Hx,
    const float* __restrict__ W1, const float* __restrict__ b1,
    const float* __restrict__ W2, const float* __restrict__ b2,
    const float* __restrict__ W3, const float* __restrict__ b3,
    const unsigned* __restrict__ row_off_g,
    const unsigned* __restrict__ packed_g,
    const unsigned* __restrict__ nor_g,
    float* __restrict__ out)
{
    __shared__ short    Ab[NUMK * ASTRIDE];     // Â bf16; later aliased by a1bf
    __shared__ unsigned pk[NSLOT];
    __shared__ float    wshp[NE + 1];           // edge weights; [NE] = 1 (self)
    __shared__ short    W2T[HID * A1STRIDE];    // W2T[jj][j] bf16
    __shared__ float    pbuf[NUMK], dinv[NUMK], a0s[NUMK], sbuf[NUMK];
    __shared__ unsigned roff[NUMK + 1], norb[NUMK];
    __shared__ float    w1s[HID], b1s[HID], b2s[HID], w3s[HID];

    const int tid = threadIdx.x;
    const float* rowp = Hx + (size_t)blockIdx.x * ROWLEN;

    // ---- P1: stage + zero Â ----
    for (int t = tid; t < (NUMK * ASTRIDE) / 8; t += 256)
        *(s8*)&Ab[t * 8] = (s8)0;
    if (tid < NUMK) {
        const unsigned nid = nor_g[tid];
        norb[tid] = nid;
        pbuf[tid] = rowp[nid];
    }
    for (int t = tid; t < NE / 2; t += 256)
        *(float2*)&wshp[2 * t] = *(const float2*)&rowp[NUMK + 2 * t];
    if (tid == 0) wshp[NE] = 1.0f;
    for (int t = tid; t < NSLOT / 2; t += 256)
        *(uint2*)&pk[2 * t] = *(const uint2*)&packed_g[2 * t];
    if (tid <= NUMK) roff[tid] = row_off_g[tid];
    for (int t = tid; t < HID * HID; t += 256) {
        const int j = t >> 5, jj = t & 31;
        W2T[jj * A1STRIDE + j] = (short)f2bf(W2[t]);
    }
    if (tid < HID) {
        w1s[tid] = W1[tid]; b1s[tid] = b1[tid];
        b2s[tid] = b2[tid]; w3s[tid] = W3[tid];
    }
    __syncthreads();

    // ---- P2: degree -> dinv (rank space) ----
    if (tid < NUMK) {
        const unsigned k0 = roff[tid], k1 = roff[tid + 1];
        float d = 0.f;
        for (unsigned k = k0; k < k1; ++k) d += wshp[pk[k] >> 7];
        dinv[tid] = rsqrtf(d);                  // deg >= 1 always
    }
    __syncthreads();

    // ---- P3: norms + a0 + Â row scatter (thread r owns row r: RMW safe) ----
    if (tid < NUMK) {
        const float di = dinv[tid];
        const unsigned k0 = roff[tid], k1 = roff[tid + 1];
        float acc = 0.f;
        short* rowA = &Ab[tid * ASTRIDE];
        for (unsigned k = k0; k < k1; ++k) {
            const unsigned u = pk[k];
            const int sr = (int)(u & (NUMK - 1));
            const float nv = di * dinv[sr] * wshp[u >> 7];
            acc = fmaf(nv, pbuf[sr], acc);
            // accumulate (duplicate (src,dst) template edges exist!)
            rowA[sr] = (short)f2bf(bf2f((unsigned short)rowA[sr]) + nv);
        }
        a0s[tid] = acc;
    }
    __syncthreads();

    // ---- P4: a1 = Â @ x1, x1[k][j] = relu(a0[k]*w1[j]+b1[j]) on the fly ----
    const int wv = tid >> 6;          // wave 0..3 -> rows [32wv, 32wv+32)
    const int l  = tid & 15;          // n index within 16-tile
    const int q  = (tid & 63) >> 4;   // quad 0..3 -> k-chunk / C-row group
    f4 acc[2][2] = {{{0.f,0.f,0.f,0.f},{0.f,0.f,0.f,0.f}},
                    {{0.f,0.f,0.f,0.f},{0.f,0.f,0.f,0.f}}};
    {
        const float w1a = w1s[l],      b1a = b1s[l];
        const float w1b = w1s[l + 16], b1b = b1s[l + 16];
        #pragma unroll
        for (int ks = 0; ks < 4; ++ks) {
            const int kb = 32 * ks + 8 * q;
            const s8 Am0 = *(const s8*)&Ab[(32 * wv      + l) * ASTRIDE + kb];
            const s8 Am1 = *(const s8*)&Ab[(32 * wv + 16 + l) * ASTRIDE + kb];
            const fl4 p0 = *(const fl4*)&a0s[kb];
            const fl4 p1 = *(const fl4*)&a0s[kb + 4];
            union { s8 v; unsigned u[4]; } B0, B1;
            #pragma unroll
            for (int e = 0; e < 4; ++e) {
                const float a0e = (e < 2) ? p0[2*e]     : p1[2*e - 4];
                const float a1e = (e < 2) ? p0[2*e + 1] : p1[2*e - 3];
                float xa0 = fmaf(a0e, w1a, b1a); xa0 = fmaxf(xa0, 0.f);
                float xa1 = fmaf(a1e, w1a, b1a); xa1 = fmaxf(xa1, 0.f);
                float xb0 = fmaf(a0e, w1b, b1b); xb0 = fmaxf(xb0, 0.f);
                float xb1 = fmaf(a1e, w1b, b1b); xb1 = fmaxf(xb1, 0.f);
                B0.u[e] = (unsigned)f2bf(xa0) | ((unsigned)f2bf(xa1) << 16);
                B1.u[e] = (unsigned)f2bf(xb0) | ((unsigned)f2bf(xb1) << 16);
            }
            acc[0][0] = __builtin_amdgcn_mfma_f32_16x16x32_bf16(Am0, B0.v, acc[0][0], 0, 0, 0);
            acc[0][1] = __builtin_amdgcn_mfma_f32_16x16x32_bf16(Am0, B1.v, acc[0][1], 0, 0, 0);
            acc[1][0] = __builtin_amdgcn_mfma_f32_16x16x32_bf16(Am1, B0.v, acc[1][0], 0, 0, 0);
            acc[1][1] = __builtin_amdgcn_mfma_f32_16x16x32_bf16(Am1, B1.v, acc[1][1], 0, 0, 0);
        }
    }
    __syncthreads();    // everyone done reading Â

    // ---- P5: a1 (C layout) -> LDS bf16, reusing Â region ----
    short* a1bf = Ab;   // [128][A1STRIDE]
    #pragma unroll
    for (int mt = 0; mt < 2; ++mt)
        #pragma unroll
        for (int nt = 0; nt < 2; ++nt)
            #pragma unroll
            for (int r = 0; r < 4; ++r) {
                const int i = 32 * wv + 16 * mt + 4 * q + r;
                const int j = 16 * nt + l;
                a1bf[i * A1STRIDE + j] = (short)f2bf(acc[mt][nt][r]);
            }
    __syncthreads();

    // ---- P6: x2 = relu(a1 @ W2 + b2); s = x2 @ W3 via shfl reduce ----
    {
        f4 ac2[2][2] = {{{0.f,0.f,0.f,0.f},{0.f,0.f,0.f,0.f}},
                        {{0.f,0.f,0.f,0.f},{0.f,0.f,0.f,0.f}}};
        const s8 A0  = *(const s8*)&a1bf[(32 * wv      + l) * A1STRIDE + 8 * q];
        const s8 A1  = *(const s8*)&a1bf[(32 * wv + 16 + l) * A1STRIDE + 8 * q];
        const s8 Bw0 = *(const s8*)&W2T[(l)      * A1STRIDE + 8 * q];
        const s8 Bw1 = *(const s8*)&W2T[(16 + l) * A1STRIDE + 8 * q];
        ac2[0][0] = __builtin_amdgcn_mfma_f32_16x16x32_bf16(A0, Bw0, ac2[0][0], 0, 0, 0);
        ac2[0][1] = __builtin_amdgcn_mfma_f32_16x16x32_bf16(A0, Bw1, ac2[0][1], 0, 0, 0);
        ac2[1][0] = __builtin_amdgcn_mfma_f32_16x16x32_bf16(A1, Bw0, ac2[1][0], 0, 0, 0);
        ac2[1][1] = __builtin_amdgcn_mfma_f32_16x16x32_bf16(A1, Bw1, ac2[1][1], 0, 0, 0);

        const float b2a = b2s[l], b2b = b2s[l + 16];
        const float w3a = w3s[l], w3b = w3s[l + 16];
        #pragma unroll
        for (int mt = 0; mt < 2; ++mt)
            #pragma unroll
            for (int r = 0; r < 4; ++r) {
                const float v0 = fmaxf(ac2[mt][0][r] + b2a, 0.f);
                const float v1 = fmaxf(ac2[mt][1][r] + b2b, 0.f);
                float sv = v0 * w3a + v1 * w3b;
                #pragma unroll
                for (int m = 1; m < 16; m <<= 1) sv += __shfl_xor(sv, m, 16);
                if (l == 0) sbuf[32 * wv + 16 * mt + 4 * q + r] = sv;
            }
    }
    __syncthreads();

    // ---- P7: out = Agg(s) + b3 (norms recomputed inline) ----
    if (tid < NUMK) {
        const float di = dinv[tid];
        const unsigned k0 = roff[tid], k1 = roff[tid + 1];
        float acc7 = 0.f;
        for (unsigned k = k0; k < k1; ++k) {
            const unsigned u = pk[k];
            const int sr = (int)(u & (NUMK - 1));
            acc7 = fmaf(di * dinv[sr] * wshp[u >> 7], sbuf[sr], acc7);
        }
        out[(size_t)blockIdx.x * NUMK + norb[tid]] = acc7 + b3[0];
    }
}

extern "C" void kernel_launch(void* const* d_in, const int* in_sizes, int n_in,
                              void* d_out, int out_size, void* d_ws, size_t ws_size,
                              hipStream_t stream) {
    const float* Hx = (const float*)d_in[0];
    const int*   ei = (const int*)d_in[1];
    const float* W1 = (const float*)d_in[2];
    const float* b1 = (const float*)d_in[3];
    const float* W2 = (const float*)d_in[4];
    const float* b2 = (const float*)d_in[5];
    const float* W3 = (const float*)d_in[6];
    const float* b3 = (const float*)d_in[7];
    float* out = (float*)d_out;

    unsigned* packed  = (unsigned*)d_ws;           // [NSLOT]
    unsigned* row_off = packed + NSLOT;            // [NUMK+1]
    unsigned* nor     = row_off + (NUMK + 1);      // [NUMK]

    build_csr_kernel<<<1, 1024, 0, stream>>>(ei, row_off, packed, nor);
    gcn_main_kernel<<<NB, 256, 0, stream>>>(Hx, W1, b1, W2, b2, W3, b3,
                                            row_off, packed, nor, out);
}